// Round 6
// baseline (649.918 us; speedup 1.0000x reference)
//
#include <hip/hip_runtime.h>
#include <hip/hip_bf16.h>
#include <stdint.h>

// Problem constants
#define BATCH   8192
#define IN_DIM  1024
#define N_HID   2048
#define OUT_DIM 256
#define SRC_DIM 3072

// Tiling
#define C     16                   // source columns per chunk
#define RB    32                   // rows per row-block (= rows per wave)
#define S1_CH (IN_DIM / C)         // 64
#define S1_RB (N_HID / RB)         // 64
#define S2_CH (SRC_DIM / C)        // 192
#define S2_RB (OUT_DIM / RB)       // 8
#define NSEG1 (S1_RB * S1_CH)      // 4096
#define NSEG2 (S2_RB * S2_CH)      // 1536
// Segment: plane-0 = u16 per row (2 slot bytes, 16 u32); overflow planes
// p=1..4 = u32 per row (4 slot bytes, 32 u32 each). Slot byte = t*16+c
// (0..63); pad = 0x40 -> As zero page.
#define SEG_U32 (16 + 4 * 32)      // 144 u32 = 576 B
#define ZSLOT 64
#define PAD4  0x40404040u

// LEARNED (R1/R4/R5, measured): on this toolchain the 2nd __launch_bounds__
// arg behaves as BLOCKS/CU: cap = 512 VGPR / (arg * waves_per_block / 4).
// 512-thr: arg4 -> 64 VGPR (spilled acc!), arg2 -> 128. Here 256-thr arg6
// -> cap ~85; kernel needs ~60 (acc[32] + temps) -> no spill, ~24 waves/CU.

// ---------------------------------------------------------------------------
// k_prep: one wave per (row-block, chunk) segment. Lane r (<32) scans its
// row's 16 codes; first 2 edges -> plane-0 u16, rest -> 4-slot planes.
// Pads come from the 0x40 memset. hdr = total planes W (>=1).
// ---------------------------------------------------------------------------
__global__ void k_prep(const int* __restrict__ mat,
                       uint32_t* __restrict__ seg1, uint32_t* __restrict__ seg2,
                       uint32_t* __restrict__ hdr1, uint32_t* __restrict__ hdr2) {
    int wid  = (blockIdx.x * blockDim.x + threadIdx.x) >> 6;
    int lane = threadIdx.x & 63;
    if (wid >= NSEG1 + NSEG2) return;

    int row0, col0;
    uint32_t *seg, *hdr;
    if (wid < NSEG1) {
        int rb = wid / S1_CH, ch = wid % S1_CH;
        row0 = rb * RB;          col0 = ch * C;
        seg = seg1 + (size_t)wid * SEG_U32;  hdr = hdr1 + wid;
    } else {
        int s  = wid - NSEG1;
        int rb = s / S2_CH, ch = s % S2_CH;
        row0 = N_HID + rb * RB;  col0 = ch * C;
        seg = seg2 + (size_t)s * SEG_U32;    hdr = hdr2 + s;
    }

    int n = 0;
    if (lane < RB) {
        const int* mrow = mat + (size_t)(row0 + lane) * SRC_DIM + col0;
        uint8_t* sb = (uint8_t*)seg;
        for (int c = 0; c < C; c++) {
            int code = mrow[c];
            if (code != 0) {
                uint8_t slot = (uint8_t)((code - 1) * C + c);
                if (n < 2) {
                    sb[lane * 2 + n] = slot;            // plane-0 u16
                } else {
                    int j = n - 2;
                    sb[(size_t)(16 + (j >> 2) * 32 + lane) * 4 + (j & 3)] = slot;
                }
                n++;
            }
        }
    }
    int m = n;
    #pragma unroll
    for (int d = 1; d < 64; d <<= 1) m = max(m, __shfl_xor(m, d));
    if (lane == 0) *hdr = (m <= 2) ? 1u : (uint32_t)(1 + ((m - 2 + 3) >> 2));
}

// A-tile: As[slot*64 + lane] f32; slot = t*16+c; slot 64 = zero page.
__device__ __forceinline__ void write_acts(float* As, int c, int lane, float v) {
    As[(0 * C + c) * 64 + lane] = v;
    As[(1 * C + c) * 64 + lane] = fmaxf(v, 0.0f);
    As[(2 * C + c) * 64 + lane] = 1.0f - 2.0f / (__expf(2.0f * v) + 1.0f); // tanh
    As[(3 * C + c) * 64 + lane] = 1.0f / (1.0f + __expf(-v));              // sigmoid
}

// plane-0: one u32 covers 2 rows (2 slots each) -> straight-line, 64
// independent ds_reads per wave-chunk. Overflow planes: per-row scalar-gated.
#define EDGE_PLANES(SEGBASE, WVAL)                                             \
    {                                                                          \
        const uint32_t* rec_ = (SEGBASE);                                      \
        _Pragma("unroll")                                                      \
        for (int rr = 0; rr < 16; rr++) {                                      \
            uint32_t g2 = rec_[rr];                                            \
            acc[2 * rr]     += As[(g2 & 255u) * 64 + lane];                    \
            acc[2 * rr]     += As[((g2 >> 8) & 255u) * 64 + lane];             \
            acc[2 * rr + 1] += As[((g2 >> 16) & 255u) * 64 + lane];            \
            acc[2 * rr + 1] += As[(g2 >> 24) * 64 + lane];                     \
        }                                                                      \
        for (uint32_t p = 1; p < (WVAL); p++) {                                \
            const uint32_t* rp_ = rec_ + 16 + (p - 1) * 32;                    \
            _Pragma("unroll")                                                  \
            for (int r = 0; r < RB; r++) {                                     \
                uint32_t g = rp_[r];                                           \
                if (g != PAD4) {                                               \
                    float a = acc[r];                                          \
                    a += As[(g & 255u) * 64 + lane];                           \
                    a += As[((g >> 8) & 255u) * 64 + lane];                    \
                    a += As[((g >> 16) & 255u) * 64 + lane];                   \
                    a += As[(g >> 24) * 64 + lane];                            \
                    acc[r] = a;                                                \
                }                                                              \
            }                                                                  \
        }                                                                      \
    }

// ---------------------------------------------------------------------------
// Stage 1: block = 256 thr = 4 waves x 32 rows = 128 rows; lanes = 64 batch.
// Grid (128 batch tiles, 16 row splits). hidden stored transposed [row][b].
// ---------------------------------------------------------------------------
__global__ __launch_bounds__(256, 6) void k_hid(const float* __restrict__ x,
                                                const float* __restrict__ wp,
                                                const uint32_t* __restrict__ seg1,
                                                const uint32_t* __restrict__ hdr1,
                                                __hip_bfloat16* __restrict__ hidden_t) {
    __shared__ float As[(4 * C + 1) * 64];   // 16.6 KB (incl. zero page)
    __shared__ float xs[64][C + 1];          // 4.4 KB

    const float w  = wp[0];
    const int tile = blockIdx.x;             // 0..127
    const int lane = threadIdx.x & 63;
    const int wv   = __builtin_amdgcn_readfirstlane(threadIdx.x >> 6); // 0..3
    const int rb   = blockIdx.y * 4 + wv;    // 0..63

    if (threadIdx.x < 64) As[ZSLOT * 64 + threadIdx.x] = 0.0f;

    float acc[RB];
    #pragma unroll
    for (int r = 0; r < RB; r++) acc[r] = 0.0f;

    #pragma unroll 1
    for (int ch = 0; ch < S1_CH; ch++) {
        __syncthreads();
        {   // stage x tile 64b x 16c: one float4 per thread, coalesced
            int b  = threadIdx.x >> 2;
            int c4 = (threadIdx.x & 3) * 4;
            float4 v = *(const float4*)&x[(size_t)(tile * 64 + b) * IN_DIM + ch * C + c4];
            xs[b][c4 + 0] = v.x; xs[b][c4 + 1] = v.y;
            xs[b][c4 + 2] = v.z; xs[b][c4 + 3] = v.w;
        }
        __syncthreads();
        #pragma unroll
        for (int j = 0; j < 4; j++) {
            int c = wv * 4 + j;
            write_acts(As, c, lane, w * xs[lane][c]);
        }
        __syncthreads();
        int sidx = rb * S1_CH + ch;
        uint32_t W = hdr1[sidx];
        EDGE_PLANES(seg1 + (size_t)sidx * SEG_U32, W)
    }

    const int b = tile * 64 + lane;
    const int row0 = rb * RB;
    #pragma unroll
    for (int r = 0; r < RB; r++)
        hidden_t[(size_t)(row0 + r) * BATCH + b] = __float2bfloat16(acc[r]);
}

// ---------------------------------------------------------------------------
// Stage 2: block = 256 thr = 4 waves x 32 rows = 128 out rows.
// Grid (128 tiles, 8): y = rsplit (0..1) + 2*cg (0..3), 48 chunks per cg.
// Coalesced fp32 partials [cg][row][batch].
// ---------------------------------------------------------------------------
__global__ __launch_bounds__(256, 6) void k_out(const float* __restrict__ x,
                                                const __hip_bfloat16* __restrict__ hidden_t,
                                                const float* __restrict__ wp,
                                                const uint32_t* __restrict__ seg2,
                                                const uint32_t* __restrict__ hdr2,
                                                float* __restrict__ partials) {
    __shared__ float As[(4 * C + 1) * 64];
    __shared__ float xs[64][C + 1];

    const float w  = wp[0];
    const int tile   = blockIdx.x;           // 0..127
    const int rsplit = blockIdx.y & 1;       // 0..1
    const int cg     = blockIdx.y >> 1;      // 0..3
    const int lane = threadIdx.x & 63;
    const int wv   = __builtin_amdgcn_readfirstlane(threadIdx.x >> 6); // 0..3
    const int rb   = rsplit * 4 + wv;        // 0..7

    if (threadIdx.x < 64) As[ZSLOT * 64 + threadIdx.x] = 0.0f;

    float acc[RB];
    #pragma unroll
    for (int r = 0; r < RB; r++) acc[r] = 0.0f;

    #pragma unroll 1
    for (int cj = 0; cj < 48; cj++) {
        int ch   = cg * 48 + cj;
        int col0 = ch * C;
        __syncthreads();
        if (col0 < IN_DIM) {                 // x region: float4, coalesced
            int b  = threadIdx.x >> 2;
            int c4 = (threadIdx.x & 3) * 4;
            float4 v = *(const float4*)&x[(size_t)(tile * 64 + b) * IN_DIM + col0 + c4];
            xs[b][c4 + 0] = v.x; xs[b][c4 + 1] = v.y;
            xs[b][c4 + 2] = v.z; xs[b][c4 + 3] = v.w;
        } else {                             // hidden_t: coalesced along b
            int b  = threadIdx.x & 63;
            int c0 = threadIdx.x >> 6;       // 0..3
            #pragma unroll
            for (int k = 0; k < 4; k++) {
                int c = c0 + 4 * k;
                xs[b][c] = __bfloat162float(
                    hidden_t[(size_t)(col0 - IN_DIM + c) * BATCH + tile * 64 + b]);
            }
        }
        __syncthreads();
        #pragma unroll
        for (int j = 0; j < 4; j++) {
            int c = wv * 4 + j;
            write_acts(As, c, lane, w * xs[lane][c]);
        }
        __syncthreads();
        int sidx = rb * S2_CH + ch;
        uint32_t W = hdr2[sidx];
        EDGE_PLANES(seg2 + (size_t)sidx * SEG_U32, W)
    }

    const int b = tile * 64 + lane;
    #pragma unroll
    for (int r = 0; r < RB; r++)
        partials[((size_t)cg * OUT_DIM + rb * RB + r) * BATCH + b] = acc[r];
}

// ---------------------------------------------------------------------------
// k_sum: reduce 4 partial planes + transpose [r][b] -> out[b][r] (float4).
// ---------------------------------------------------------------------------
__global__ __launch_bounds__(256) void k_sum(const float* __restrict__ partials,
                                             float* __restrict__ out) {
    __shared__ float t[16][65];
    const int b0 = blockIdx.x * 64, r0 = blockIdx.y * 16;
    const int lane = threadIdx.x & 63;
    const int g4   = threadIdx.x >> 6;

    #pragma unroll
    for (int k = 0; k < 4; k++) {
        int rr = g4 * 4 + k;
        float s = 0.0f;
        #pragma unroll
        for (int cg = 0; cg < 4; cg++)
            s += partials[((size_t)cg * OUT_DIM + r0 + rr) * BATCH + b0 + lane];
        t[rr][lane] = s;
    }
    __syncthreads();
    int bb = threadIdx.x >> 2, rq = threadIdx.x & 3;
    float4 v;
    v.x = t[rq * 4 + 0][bb];
    v.y = t[rq * 4 + 1][bb];
    v.z = t[rq * 4 + 2][bb];
    v.w = t[rq * 4 + 3][bb];
    *(float4*)&out[(size_t)(b0 + bb) * OUT_DIM + r0 + rq * 4] = v;
}

// ---------------------------------------------------------------------------
extern "C" void kernel_launch(void* const* d_in, const int* in_sizes, int n_in,
                              void* d_out, int out_size, void* d_ws, size_t ws_size,
                              hipStream_t stream) {
    const float* x   = (const float*)d_in[0];
    const float* w   = (const float*)d_in[1];
    const int*   mat = (const int*)d_in[2];
    float* out = (float*)d_out;

    uint8_t* ws = (uint8_t*)d_ws;
    size_t off = 0;
    __hip_bfloat16* hidden_t = (__hip_bfloat16*)(ws + off); off += (size_t)BATCH * N_HID * 2;  // 33.55 MB
    uint32_t* seg1 = (uint32_t*)(ws + off); off += (size_t)NSEG1 * SEG_U32 * 4;                //  2.36 MB
    uint32_t* seg2 = (uint32_t*)(ws + off); off += (size_t)NSEG2 * SEG_U32 * 4;                //  0.88 MB
    uint32_t* hdr1 = (uint32_t*)(ws + off); off += (size_t)NSEG1 * 4;
    uint32_t* hdr2 = (uint32_t*)(ws + off); off += (size_t)NSEG2 * 4;
    float* partials = (float*)(ws + off);   off += (size_t)4 * OUT_DIM * BATCH * 4;            // 33.55 MB
    (void)ws_size; (void)in_sizes; (void)n_in; (void)out_size;

    // pad-fill both seg regions (contiguous) with 0x40 slot bytes
    hipMemsetAsync(seg1, 0x40, (size_t)(NSEG1 + NSEG2) * SEG_U32 * 4, stream);

    {
        int nseg = NSEG1 + NSEG2;                   // 5632 waves
        k_prep<<<(nseg + 3) / 4, 256, 0, stream>>>(mat, seg1, seg2, hdr1, hdr2);
    }
    {
        dim3 g(BATCH / 64, 16);                     // 2048 blocks
        k_hid<<<g, 256, 0, stream>>>(x, w, seg1, hdr1, hidden_t);
    }
    {
        dim3 g(BATCH / 64, 8);                      // 1024 blocks
        k_out<<<g, 256, 0, stream>>>(x, hidden_t, w, seg2, hdr2, partials);
    }
    {
        dim3 g(BATCH / 64, OUT_DIM / 16);           // 2048 blocks
        k_sum<<<g, 256, 0, stream>>>(partials, out);
    }
}